// Round 1
// baseline (573.052 us; speedup 1.0000x reference)
//
#include <hip/hip_runtime.h>

// mLSTM (UniRep-style), T=2048, B=4096, I=1, H=5.
// Key identity (I==1): gates = x*(Wih + W3 @ h) + (b_ih+b_hh),
//   where W3[j][k] = sum_m Whh[j][m]*Wmx[m]*Wmh[m][k]  (constant 20x5).
// Parallelization: 8 lanes per batch element; lane l<5 owns hidden index l and
// computes its 4 gate rows {l, l+5, l+10, l+15} -> no cross-lane gather for the
// cell update; only a 5-value h broadcast per step (width-8 shuffles).

#define TT 2048
#define BB 4096
#define HH 5

__global__ __launch_bounds__(64) void mlstm_kernel(
    const float* __restrict__ xb,    // [T, B, 1]
    const float* __restrict__ h0,    // [B, H]
    const float* __restrict__ c0,    // [B, H]
    const float* __restrict__ Wmx,   // [H, 1]
    const float* __restrict__ Wmh,   // [H, H]
    const float* __restrict__ Wih,   // [4H, 1]
    const float* __restrict__ Whh,   // [4H, H]
    const float* __restrict__ b_ih,  // [4H]
    const float* __restrict__ b_hh,  // [4H]
    float* __restrict__ out)         // [B, H] = relu(h_T)
{
    const int tid  = blockIdx.x * 64 + threadIdx.x;
    const int lane = threadIdx.x & 7;                 // lane within 8-lane group
    const int b    = tid >> 3;                        // batch element
    const int l    = (lane < HH) ? lane : (lane - HH); // effective hidden idx (lanes 5-7 duplicate)

    // ---- one-time per-thread weight fold (amortized over 2048 steps) ----
    float W3[4][HH], wih[4], bias[4];
#pragma unroll
    for (int q = 0; q < 4; ++q) {                     // q: 0=i 1=f 2=g 3=o
        const int r = l + HH * q;                     // gate row
        wih[q]  = Wih[r];
        bias[q] = b_ih[r] + b_hh[r];
#pragma unroll
        for (int k = 0; k < HH; ++k) {
            float s = 0.f;
#pragma unroll
            for (int m = 0; m < HH; ++m)
                s = fmaf(Whh[r * HH + m] * Wmx[m], Wmh[m * HH + k], s);
            W3[q][k] = s;
        }
    }

    float c = c0[b * HH + l];
    float hk[HH];
#pragma unroll
    for (int k = 0; k < HH; ++k) hk[k] = h0[b * HH + k];

    const float NL2E  = -1.442695040888963f;   // -log2(e)
    const float N2L2E = -2.885390081777927f;   // -2*log2(e)

    float x = xb[b];          // t = 0 (xb[t*B + b], I==1)
    float h_own = 0.f;
    for (int t = 0; t < TT; ++t) {
        // prefetch next x (clamped index -> branch-free, harmless dup at end)
        const int tn = (t + 1 < TT) ? (t + 1) : (TT - 1);
        const float x_next = xb[tn * BB + b];

        // u_q = Wih_r + (W3 h)_r ; gate_q = x*u_q + bias_r
        float u0 = wih[0], u1 = wih[1], u2 = wih[2], u3 = wih[3];
#pragma unroll
        for (int k = 0; k < HH; ++k) {
            const float hv = hk[k];
            u0 = fmaf(W3[0][k], hv, u0);
            u1 = fmaf(W3[1][k], hv, u1);
            u2 = fmaf(W3[2][k], hv, u2);
            u3 = fmaf(W3[3][k], hv, u3);
        }
        const float gi_ = fmaf(x, u0, bias[0]);
        const float gf_ = fmaf(x, u1, bias[1]);
        const float gg_ = fmaf(x, u2, bias[2]);
        const float go_ = fmaf(x, u3, bias[3]);

        // sigmoid(z) = rcp(1 + exp2(-z*log2e)); tanh(z) = 2*rcp(1+exp2(-2z*log2e)) - 1
        const float gi = __builtin_amdgcn_rcpf(1.f + __builtin_amdgcn_exp2f(NL2E * gi_));
        const float gf = __builtin_amdgcn_rcpf(1.f + __builtin_amdgcn_exp2f(NL2E * gf_));
        const float gg = fmaf(2.f, __builtin_amdgcn_rcpf(1.f + __builtin_amdgcn_exp2f(N2L2E * gg_)), -1.f);
        const float go = __builtin_amdgcn_rcpf(1.f + __builtin_amdgcn_exp2f(NL2E * go_));

        c = fmaf(gf, c, gi * gg);
        const float tc = fmaf(2.f, __builtin_amdgcn_rcpf(1.f + __builtin_amdgcn_exp2f(N2L2E * c)), -1.f);
        h_own = go * tc;

        // broadcast the 5 new h values to all 8 lanes of the group
#pragma unroll
        for (int k = 0; k < HH; ++k) hk[k] = __shfl(h_own, k, 8);

        x = x_next;
    }

    if (lane < HH) out[b * HH + lane] = fmaxf(h_own, 0.f);
}

extern "C" void kernel_launch(void* const* d_in, const int* in_sizes, int n_in,
                              void* d_out, int out_size, void* d_ws, size_t ws_size,
                              hipStream_t stream) {
    const float* xb   = (const float*)d_in[0];
    const float* h0   = (const float*)d_in[1];
    const float* c0   = (const float*)d_in[2];
    const float* Wmx  = (const float*)d_in[3];
    const float* Wmh  = (const float*)d_in[4];
    const float* Wih  = (const float*)d_in[5];
    const float* Whh  = (const float*)d_in[6];
    const float* b_ih = (const float*)d_in[7];
    const float* b_hh = (const float*)d_in[8];
    float* out = (float*)d_out;

    const int threads = BB * 8;          // 8 lanes per batch element
    const int block   = 64;              // one wave per block -> spreads 512 blocks over 256 CUs
    const int grid    = threads / block; // 512
    mlstm_kernel<<<grid, block, 0, stream>>>(xb, h0, c0, Wmx, Wmh, Wih, Whh, b_ih, b_hh, out);
}

// Round 2
// 311.747 us; speedup vs baseline: 1.8382x; 1.8382x over previous
//
#include <hip/hip_runtime.h>

// mLSTM (UniRep-style), T=2048, B=4096, I=1, H=5.
// Identity (I==1): gates = x*(Wih + W3 @ h) + (b_ih+b_hh),
//   W3[j][k] = sum_m Whh[j][m]*Wmx[m]*Wmh[m][k]  (constant 20x5) -> plain LSTM cell.
// 8 lanes per batch element; lane l<5 owns hidden idx l and its 4 gate rows.
// All activation inputs pre-scaled by -log2e (-2log2e for g); c kept in the
// -2log2e domain so tanh(c) = 2*rcp(1+exp2(cs))-1 with no mul on the chain.
// h broadcast via DPP (VALU) instead of ds_bpermute; x prefetched 8 steps deep.

#define TT 2048
#define BB 4096
#define HH 5

template<int CTRL, int RM, int BM>
__device__ __forceinline__ float dpp_upd(float old_, float src) {
    int o = __builtin_bit_cast(int, old_);
    int s = __builtin_bit_cast(int, src);
    int r = __builtin_amdgcn_update_dpp(o, s, CTRL, RM, BM, false);
    return __builtin_bit_cast(float, r);
}

__global__ __launch_bounds__(64) void mlstm_kernel(
    const float* __restrict__ xb,    // [T, B]
    const float* __restrict__ h0,    // [B, H]
    const float* __restrict__ c0,    // [B, H]
    const float* __restrict__ Wmx,   // [H]
    const float* __restrict__ Wmh,   // [H, H]
    const float* __restrict__ Wih,   // [4H]
    const float* __restrict__ Whh,   // [4H, H]
    const float* __restrict__ b_ih,  // [4H]
    const float* __restrict__ b_hh,  // [4H]
    float* __restrict__ out)         // [B, H] = relu(h_T)
{
    const int tid  = blockIdx.x * 64 + threadIdx.x;
    const int l8   = threadIdx.x & 7;
    const int b    = tid >> 3;
    const int l    = (l8 < HH) ? l8 : (l8 - HH);   // lanes 5-7 duplicate (outputs unused)

    const float NL2E  = -1.442695040888963f;   // -log2(e)
    const float N2L2E = -2.885390081777927f;   // -2*log2(e)
    const float K2    = 2.f * N2L2E;           // for ggs = N2L2E*tanh(g)
    const float K3    = -N2L2E;

    // ---- one-time per-thread weight fold, pre-scaled ----
    float W3[4][HH], wih[4], bias[4];
#pragma unroll
    for (int q = 0; q < 4; ++q) {                  // 0=i 1=f 2=g 3=o
        const float sq = (q == 2) ? N2L2E : NL2E;
        const int r = l + HH * q;
        wih[q]  = sq * Wih[r];
        bias[q] = sq * (b_ih[r] + b_hh[r]);
#pragma unroll
        for (int k = 0; k < HH; ++k) {
            float s = 0.f;
#pragma unroll
            for (int m = 0; m < HH; ++m)
                s = fmaf(Whh[r * HH + m] * Wmx[m], Wmh[m * HH + k], s);
            W3[q][k] = sq * s;
        }
    }

    float cs = N2L2E * c0[b * HH + l];   // c in scaled domain
    float hk[HH];
#pragma unroll
    for (int k = 0; k < HH; ++k) hk[k] = h0[b * HH + k];

    float h_own = 0.f;

    // ---- x prefetch: 8-step blocks, double-buffered in registers ----
    float xc[8], xn[8];
#pragma unroll
    for (int j = 0; j < 8; ++j) xc[j] = xb[j * BB + b];

    for (int tb = 0; tb < TT / 8; ++tb) {
        const int tn = (tb + 1 < TT / 8) ? (tb + 1) : tb;   // clamped: harmless reload
#pragma unroll
        for (int j = 0; j < 8; ++j) xn[j] = xb[(tn * 8 + j) * BB + b];

#pragma unroll
        for (int j = 0; j < 8; ++j) {
            const float xv = xc[j];
            // u_q = wih_q + (W3 h)_q   (3+2 split to shorten the chain)
            float ua0 = fmaf(W3[0][0], hk[0], wih[0]);
            float ua1 = fmaf(W3[1][0], hk[0], wih[1]);
            float ua2 = fmaf(W3[2][0], hk[0], wih[2]);
            float ua3 = fmaf(W3[3][0], hk[0], wih[3]);
            ua0 = fmaf(W3[0][1], hk[1], ua0);  ua0 = fmaf(W3[0][2], hk[2], ua0);
            ua1 = fmaf(W3[1][1], hk[1], ua1);  ua1 = fmaf(W3[1][2], hk[2], ua1);
            ua2 = fmaf(W3[2][1], hk[1], ua2);  ua2 = fmaf(W3[2][2], hk[2], ua2);
            ua3 = fmaf(W3[3][1], hk[1], ua3);  ua3 = fmaf(W3[3][2], hk[2], ua3);
            float ub0 = W3[0][3] * hk[3];  ub0 = fmaf(W3[0][4], hk[4], ub0);
            float ub1 = W3[1][3] * hk[3];  ub1 = fmaf(W3[1][4], hk[4], ub1);
            float ub2 = W3[2][3] * hk[3];  ub2 = fmaf(W3[2][4], hk[4], ub2);
            float ub3 = W3[3][3] * hk[3];  ub3 = fmaf(W3[3][4], hk[4], ub3);
            const float g0 = fmaf(xv, ua0 + ub0, bias[0]);
            const float g1 = fmaf(xv, ua1 + ub1, bias[1]);
            const float g2 = fmaf(xv, ua2 + ub2, bias[2]);
            const float g3 = fmaf(xv, ua3 + ub3, bias[3]);

            const float gi = __builtin_amdgcn_rcpf(1.f + __builtin_amdgcn_exp2f(g0));
            const float gf = __builtin_amdgcn_rcpf(1.f + __builtin_amdgcn_exp2f(g1));
            const float rg = __builtin_amdgcn_rcpf(1.f + __builtin_amdgcn_exp2f(g2));
            const float go = __builtin_amdgcn_rcpf(1.f + __builtin_amdgcn_exp2f(g3));
            const float ggs = fmaf(K2, rg, K3);          // = N2L2E * tanh(g)

            cs = fmaf(gf, cs, gi * ggs);                 // scaled-domain c update
            const float tc = fmaf(2.f, __builtin_amdgcn_rcpf(1.f + __builtin_amdgcn_exp2f(cs)), -1.f);
            h_own = go * tc;

            // ---- DPP broadcast of h0..h4 to all 8 lanes of the group ----
            // owners: lanes 8g+0..3 (even bank) hold h0..h3; lane 8g+4 holds h4.
            // k<4: even banks via quad_perm[k,k,k,k]; odd banks via row_shr:(4-k)
            //      (exact for the lane-4 owner; lanes 5-7 get junk, never read).
            hk[0] = dpp_upd<0x00, 0xF, 0x5>(h_own, h_own);
            hk[0] = dpp_upd<0x114, 0xF, 0xA>(hk[0], h_own);  // row_shr:4
            hk[1] = dpp_upd<0x55, 0xF, 0x5>(h_own, h_own);
            hk[1] = dpp_upd<0x113, 0xF, 0xA>(hk[1], h_own);  // row_shr:3
            hk[2] = dpp_upd<0xAA, 0xF, 0x5>(h_own, h_own);
            hk[2] = dpp_upd<0x112, 0xF, 0xA>(hk[2], h_own);  // row_shr:2
            hk[3] = dpp_upd<0xFF, 0xF, 0x5>(h_own, h_own);
            hk[3] = dpp_upd<0x111, 0xF, 0xA>(hk[3], h_own);  // row_shr:1
            // h4: even banks: row_shl:4 (lane 8g <- 8g+4) then quad_perm0;
            //     odd banks: quad_perm0 of h_own (their quad base IS lane 8g+4).
            float t4 = dpp_upd<0x104, 0xF, 0x5>(h_own, h_own); // row_shl:4
            t4 = dpp_upd<0x00, 0xF, 0x5>(t4, t4);
            hk[4] = dpp_upd<0x00, 0xF, 0xA>(t4, h_own);
        }

#pragma unroll
        for (int j = 0; j < 8; ++j) xc[j] = xn[j];
    }

    if (l8 < HH) out[b * HH + l8] = fmaxf(h_own, 0.f);
}

extern "C" void kernel_launch(void* const* d_in, const int* in_sizes, int n_in,
                              void* d_out, int out_size, void* d_ws, size_t ws_size,
                              hipStream_t stream) {
    const float* xb   = (const float*)d_in[0];
    const float* h0   = (const float*)d_in[1];
    const float* c0   = (const float*)d_in[2];
    const float* Wmx  = (const float*)d_in[3];
    const float* Wmh  = (const float*)d_in[4];
    const float* Wih  = (const float*)d_in[5];
    const float* Whh  = (const float*)d_in[6];
    const float* b_ih = (const float*)d_in[7];
    const float* b_hh = (const float*)d_in[8];
    float* out = (float*)d_out;

    const int grid = (BB * 8) / 64;   // 512 one-wave blocks over 256 CUs
    mlstm_kernel<<<grid, 64, 0, stream>>>(xb, h0, c0, Wmx, Wmh, Wih, Whh, b_ih, b_hh, out);
}

// Round 4
// 308.494 us; speedup vs baseline: 1.8576x; 1.0105x over previous
//
#include <hip/hip_runtime.h>

// mLSTM (UniRep-style), T=2048, B=4096, I=1, H=5.
// Identity (I==1): gates = x*(Wih + W3 @ h) + (b_ih+b_hh),
//   W3[r][j] = sum_k Whh[r][k]*Wmx[k]*Wmh[k][j]  (constant 20x5) -> plain LSTM cell.
//
// 16 lanes per batch chain (one DPP row). Lane l owns gate-ROW l:
//   rows 0-4 = i, 5-9 = f, 10-14 = g (lane 15 dup), o-rows 15-19 as a
//   SECONDARY dot on lanes 0-4 (dup elsewhere). One exp2+rcp instruction
//   covers all i/f/g activations; per-lane (A,B) selects sigmoid vs tanh.
//   o's rcp fused with tanh(c)'s: R = rcp((1+e_o)(1+e_c)); go = R*(1+e_c);
//   tanh(c) = fma(2(1+e_o), R, -1).
// DPP direction rule (verified via the passing R1 kernel):
//   row_shr:N -> dest lane i <- src lane i-N ; row_shl:N -> dest i <- src i+N.
// exp2 args clamped to <=126 so the fused-rcp path can never hit 0*Inf=NaN.

#define TT 2048
#define BB 4096
#define HH 5

template<int CTRL, int RM, int BM>
__device__ __forceinline__ float dpp_upd(float old_, float src) {
    int o = __builtin_bit_cast(int, old_);
    int s = __builtin_bit_cast(int, src);
    int r = __builtin_amdgcn_update_dpp(o, s, CTRL, RM, BM, false);
    return __builtin_bit_cast(float, r);
}

__global__ __launch_bounds__(64) void mlstm_kernel(
    const float* __restrict__ xb,    // [T, B]
    const float* __restrict__ h0,    // [B, H]
    const float* __restrict__ c0,    // [B, H]
    const float* __restrict__ Wmx,   // [H]
    const float* __restrict__ Wmh,   // [H, H]
    const float* __restrict__ Wih,   // [4H]
    const float* __restrict__ Whh,   // [4H, H]
    const float* __restrict__ b_ih,  // [4H]
    const float* __restrict__ b_hh,  // [4H]
    float* __restrict__ out)         // [B, H] = relu(h_T)
{
    const int tid = blockIdx.x * 64 + threadIdx.x;
    const int l16 = threadIdx.x & 15;
    const int b   = tid >> 4;

    const float NL2E  = -1.442695040888963f;   // -log2(e)
    const float N2L2E = -2.885390081777927f;   // -2*log2(e)
    const float K2    = 2.f * N2L2E;
    const float K3    = -N2L2E;

    // Row assignment: primary = own gate row (i/f/g), secondary = o row.
    const int  prow = (l16 < 15) ? l16 : 14;            // lane 15 dup (unused)
    const int  srow = 15 + ((l16 < HH) ? l16 : 4);      // o rows; dup elsewhere
    const bool is_g = (l16 >= 10);
    const float sp  = is_g ? N2L2E : NL2E;              // primary pre-scale
    const float A   = is_g ? K2 : 1.f;                  // act = A*rcp(1+e)+B
    const float Bc  = is_g ? K3 : 0.f;

    // ---- one-time per-lane weight fold (amortized over 2048 steps) ----
    float W3p[HH], W3s[HH], wihp, wihs, bp, bs;
    wihp = sp * Wih[prow];
    bp   = sp * (b_ih[prow] + b_hh[prow]);
    wihs = NL2E * Wih[srow];
    bs   = NL2E * (b_ih[srow] + b_hh[srow]);
#pragma unroll
    for (int j = 0; j < HH; ++j) {
        float s1 = 0.f, s2 = 0.f;
#pragma unroll
        for (int k = 0; k < HH; ++k) {
            const float wk = Wmx[k] * Wmh[k * HH + j];
            s1 = fmaf(Whh[prow * HH + k], wk, s1);
            s2 = fmaf(Whh[srow * HH + k], wk, s2);
        }
        W3p[j] = sp * s1;
        W3s[j] = NL2E * s2;
    }

    float cs = N2L2E * c0[b * HH + (l16 % HH)];   // owners (lanes 0-4) correct
    float hk0 = h0[b * HH + 0], hk1 = h0[b * HH + 1], hk2 = h0[b * HH + 2],
          hk3 = h0[b * HH + 3], hk4 = h0[b * HH + 4];

    float h_own = 0.f;

    // ---- x prefetch: 8-step blocks, double-buffered in registers ----
    float xc[8], xn[8];
#pragma unroll
    for (int j = 0; j < 8; ++j) xc[j] = xb[j * BB + b];

    for (int tb = 0; tb < TT / 8; ++tb) {
        const int tn = (tb + 1 < TT / 8) ? (tb + 1) : tb;   // clamped: harmless reload
#pragma unroll
        for (int j = 0; j < 8; ++j) xn[j] = xb[(tn * 8 + j) * BB + b];

#pragma unroll
        for (int j = 0; j < 8; ++j) {
            const float xv = xc[j];

            // primary & secondary dots: g = b + x*(wih + W3 . h)
            float ua = fmaf(W3p[0], hk0, wihp);
            float va = fmaf(W3s[0], hk0, wihs);
            ua = fmaf(W3p[1], hk1, ua);
            va = fmaf(W3s[1], hk1, va);
            ua = fmaf(W3p[2], hk2, ua);
            va = fmaf(W3s[2], hk2, va);
            float ub = W3p[3] * hk3;
            float vb = W3s[3] * hk3;
            ub = fmaf(W3p[4], hk4, ub);
            vb = fmaf(W3s[4], hk4, vb);
            const float gp = fmaf(xv, ua + ub, bp);
            const float gs = fmaf(xv, va + vb, bs);

            const float ep  = __builtin_amdgcn_exp2f(gp);  // all i/f/g acts at once
            const float es  = __builtin_amdgcn_exp2f(fminf(gs, 126.f));  // o-gate exp
            const float aes = 1.f + es;
            const float rp  = __builtin_amdgcn_rcpf(1.f + ep);
            const float actp = fmaf(A, rp, Bc);            // sigma(i/f) or N2L2E*tanh(g)

            // gather f (lane l <- l+5) and g (lane l <- l+10) to owner lanes 0-4
            const float fv = dpp_upd<0x105, 0xF, 0xF>(actp, actp);  // row_shl:5
            const float gv = dpp_upd<0x10A, 0xF, 0xF>(actp, actp);  // row_shl:10

            cs = fmaf(fv, cs, actp * gv);                  // i is lane-local

            const float ec  = __builtin_amdgcn_exp2f(fminf(cs, 126.f));
            const float aec = 1.f + ec;
            const float R   = __builtin_amdgcn_rcpf(aes * aec);   // fused o & tanh(c) rcp
            const float tc  = fmaf(aes + aes, R, -1.f);           // tanh(c)
            const float go  = R * aec;                            // sigma(o)
            h_own = go * tc;

            // ---- broadcast h0..h4 (owner lanes 0-4) to all 16 lanes via DPP ----
            // vq: copy quad0 (h0..h3) into banks 1,2,3 (row_shr moves data UP lanes)
            float vq = h_own;
            vq = dpp_upd<0x114, 0xF, 0x2>(vq, h_own);   // row_shr:4  lanes 4-7  <- 0-3
            vq = dpp_upd<0x118, 0xF, 0x4>(vq, h_own);   // row_shr:8  lanes 8-11 <- 0-3
            vq = dpp_upd<0x11C, 0xF, 0x8>(vq, h_own);   // row_shr:12 lanes 12-15<- 0-3
            hk0 = dpp_upd<0x00, 0xF, 0xF>(vq, vq);      // quad_perm[0,0,0,0]
            hk1 = dpp_upd<0x55, 0xF, 0xF>(vq, vq);
            hk2 = dpp_upd<0xAA, 0xF, 0xF>(vq, vq);
            hk3 = dpp_upd<0xFF, 0xF, 0xF>(vq, vq);
            // h4: lane0 <- lane4 (row_shl:4), quad_perm0 fills quad0, replicate up
            float t4 = dpp_upd<0x104, 0xF, 0xF>(h_own, h_own);  // row_shl:4
            t4 = dpp_upd<0x00, 0xF, 0xF>(t4, t4);               // quad0 = h4
            hk4 = t4;
            hk4 = dpp_upd<0x114, 0xF, 0x2>(hk4, t4);
            hk4 = dpp_upd<0x118, 0xF, 0x4>(hk4, t4);
            hk4 = dpp_upd<0x11C, 0xF, 0x8>(hk4, t4);
        }

#pragma unroll
        for (int j = 0; j < 8; ++j) xc[j] = xn[j];
    }

    if (l16 < HH) out[b * HH + l16] = fmaxf(h_own, 0.f);
}

extern "C" void kernel_launch(void* const* d_in, const int* in_sizes, int n_in,
                              void* d_out, int out_size, void* d_ws, size_t ws_size,
                              hipStream_t stream) {
    const float* xb   = (const float*)d_in[0];
    const float* h0   = (const float*)d_in[1];
    const float* c0   = (const float*)d_in[2];
    const float* Wmx  = (const float*)d_in[3];
    const float* Wmh  = (const float*)d_in[4];
    const float* Wih  = (const float*)d_in[5];
    const float* Whh  = (const float*)d_in[6];
    const float* b_ih = (const float*)d_in[7];
    const float* b_hh = (const float*)d_in[8];
    float* out = (float*)d_out;

    const int grid = (BB * 16) / 64;   // 1024 one-wave blocks, 16 lanes/chain
    mlstm_kernel<<<grid, 64, 0, stream>>>(xb, h0, c0, Wmx, Wmh, Wih, Whh, b_ih, b_hh, out);
}

// Round 5
// 298.983 us; speedup vs baseline: 1.9167x; 1.0318x over previous
//
#include <hip/hip_runtime.h>

// mLSTM (UniRep-style), T=2048, B=4096, I=1, H=5.
// Identity (I==1): gates = x*(Wih + W3 @ h) + (b_ih+b_hh),
//   W3[r][j] = sum_k Whh[r][k]*Wmx[k]*Wmh[k][j]  (constant 20x5) -> plain LSTM cell.
//
// Latency-bound regime: all 4096 chains are resident; wall = 2048 * L where L is
// the per-step serial dependency chain. This version minimizes chain ops (16):
//   8 lanes/chain; lanes 0-4 own cell j=l; lanes 5-7 DUPLICATE cell j=4 so the
//   h4 broadcast is a single row_shl:4 DPP (depth 1). hk0-3 depth 2 (qperm+shr).
//   Balanced dot trees (gate@6 from h). Safe saturating activation forms (no
//   clamps needed). cs' = K2*(ri*rg) + (rf*cs + K3*ri). h = fma(2*so, R, -so).
// Gate preacts pre-scaled by -log2e (i,f,o) / -2log2e (g); c kept in -2log2e
// domain: exp2(cs) = e^{-2c}; tanh(c) = 2*rcp(1+exp2(cs)) - 1.
// DPP rule (verified R1/R4): row_shr:N -> lane i <- i-N ; row_shl:N -> i <- i+N.

#define TT 2048
#define BB 4096
#define HH 5

template<int CTRL, int RM, int BM>
__device__ __forceinline__ float dpp_upd(float old_, float src) {
    int o = __builtin_bit_cast(int, old_);
    int s = __builtin_bit_cast(int, src);
    int r = __builtin_amdgcn_update_dpp(o, s, CTRL, RM, BM, false);
    return __builtin_bit_cast(float, r);
}

__global__ __launch_bounds__(64) void mlstm_kernel(
    const float* __restrict__ xb,    // [T, B]
    const float* __restrict__ h0,    // [B, H]
    const float* __restrict__ c0,    // [B, H]
    const float* __restrict__ Wmx,   // [H]
    const float* __restrict__ Wmh,   // [H, H]
    const float* __restrict__ Wih,   // [4H]
    const float* __restrict__ Whh,   // [4H, H]
    const float* __restrict__ b_ih,  // [4H]
    const float* __restrict__ b_hh,  // [4H]
    float* __restrict__ out)         // [B, H] = relu(h_T)
{
    const int tid = blockIdx.x * 64 + threadIdx.x;
    const int l8  = threadIdx.x & 7;
    const int b   = tid >> 3;
    const int j   = (l8 < HH) ? l8 : 4;   // lanes 5-7 duplicate cell 4

    const float NL2E  = -1.442695040888963f;   // -log2(e)
    const float N2L2E = -2.885390081777927f;   // -2*log2(e)
    const float K2 = 2.f * N2L2E;              // cs' = K2*(ri*rg) + (rf*cs + K3*ri)
    const float K3 = -N2L2E;

    // ---- one-time per-thread weight fold (amortized over 2048 steps) ----
    float W3[4][HH], wih[4], bias[4];
#pragma unroll
    for (int q = 0; q < 4; ++q) {              // 0=i 1=f 2=g 3=o ; row r = j + 5q
        const float sq = (q == 2) ? N2L2E : NL2E;
        const int r = j + HH * q;
        wih[q]  = sq * Wih[r];
        bias[q] = sq * (b_ih[r] + b_hh[r]);
#pragma unroll
        for (int k = 0; k < HH; ++k) {
            float s = 0.f;
#pragma unroll
            for (int m = 0; m < HH; ++m)
                s = fmaf(Whh[r * HH + m] * Wmx[m], Wmh[m * HH + k], s);
            W3[q][k] = sq * s;
        }
    }

    float cs = N2L2E * c0[b * HH + j];         // c in -2log2e domain
    float hk0 = h0[b * HH + 0], hk1 = h0[b * HH + 1], hk2 = h0[b * HH + 2],
          hk3 = h0[b * HH + 3], hk4 = h0[b * HH + 4];

    float h_own = 0.f;

    // ---- x prefetch: 8-step blocks, double-buffered in registers ----
    float xc[8], xn[8];
#pragma unroll
    for (int j8 = 0; j8 < 8; ++j8) xc[j8] = xb[j8 * BB + b];

    for (int tb = 0; tb < TT / 8; ++tb) {
        const int tn = (tb + 1 < TT / 8) ? (tb + 1) : tb;   // clamped: harmless reload
#pragma unroll
        for (int j8 = 0; j8 < 8; ++j8) xn[j8] = xb[(tn * 8 + j8) * BB + b];

#pragma unroll
        for (int j8 = 0; j8 < 8; ++j8) {
            const float xv = xc[j8];

            // gate preacts, balanced 2-chain trees (depth 4 from hk-ready)
            float g[4];
#pragma unroll
            for (int q = 0; q < 4; ++q) {
                const float m4 = W3[q][4] * hk4;              // hk4 ready first
                const float C  = fmaf(W3[q][3], hk3, m4);
                const float C2 = fmaf(W3[q][2], hk2, C);
                const float A  = fmaf(W3[q][0], hk0, wih[q]);
                const float A2 = fmaf(W3[q][1], hk1, A);
                g[q] = fmaf(xv, A2 + C2, bias[q]);
            }

            // activations: r = rcp(1+exp2(pre)); saturating forms, no clamps.
            const float ei = __builtin_amdgcn_exp2f(g[0]);
            const float ef = __builtin_amdgcn_exp2f(g[1]);
            const float eg = __builtin_amdgcn_exp2f(g[2]);
            const float eo = __builtin_amdgcn_exp2f(g[3]);
            const float ri = __builtin_amdgcn_rcpf(1.f + ei);  // sigma(i)
            const float rf = __builtin_amdgcn_rcpf(1.f + ef);  // sigma(f)
            const float rg = __builtin_amdgcn_rcpf(1.f + eg);  // sigma(2g)
            const float ro = __builtin_amdgcn_rcpf(1.f + eo);  // sigma(o)

            // cs' = rf*cs + ri*(K2*rg + K3)  (re-associated: rcp->cs in 3 ops)
            const float m   = ri * rg;
            const float k3i = K3 * ri;
            const float t   = fmaf(rf, cs, k3i);
            cs = fmaf(K2, m, t);

            const float s2o = ro + ro;      // off-chain epilogue constants
            const float nso = -ro;

            // h = sigma(o)*tanh(c) = 2*so*R - so,  R = rcp(1+exp2(cs))
            const float ec = __builtin_amdgcn_exp2f(cs);
            const float R  = __builtin_amdgcn_rcpf(1.f + ec);
            h_own = fmaf(s2o, R, nso);

            // ---- broadcast h0..h4 to all 8 lanes of the group ----
            // hk4: depth 1 — lanes {0-3,8-11} <- lane+4 (owners/dups of h4);
            //      lanes {4-7,12-15} keep h_own (they ARE h4). BM=0x5.
            hk4 = dpp_upd<0x104, 0xF, 0x5>(h_own, h_own);      // row_shl:4
            // hk0-3: depth 2 — qperm_k on even banks, then row_shr:4 to odd banks.
            float v0 = dpp_upd<0x00, 0xF, 0x5>(h_own, h_own);
            float v1 = dpp_upd<0x55, 0xF, 0x5>(h_own, h_own);
            float v2 = dpp_upd<0xAA, 0xF, 0x5>(h_own, h_own);
            float v3 = dpp_upd<0xFF, 0xF, 0x5>(h_own, h_own);
            hk0 = dpp_upd<0x114, 0xF, 0xA>(v0, v0);            // row_shr:4
            hk1 = dpp_upd<0x114, 0xF, 0xA>(v1, v1);
            hk2 = dpp_upd<0x114, 0xF, 0xA>(v2, v2);
            hk3 = dpp_upd<0x114, 0xF, 0xA>(v3, v3);
        }

#pragma unroll
        for (int j8 = 0; j8 < 8; ++j8) xc[j8] = xn[j8];
    }

    if (l8 < HH) out[b * HH + l8] = fmaxf(h_own, 0.f);
}

extern "C" void kernel_launch(void* const* d_in, const int* in_sizes, int n_in,
                              void* d_out, int out_size, void* d_ws, size_t ws_size,
                              hipStream_t stream) {
    const float* xb   = (const float*)d_in[0];
    const float* h0   = (const float*)d_in[1];
    const float* c0   = (const float*)d_in[2];
    const float* Wmx  = (const float*)d_in[3];
    const float* Wmh  = (const float*)d_in[4];
    const float* Wih  = (const float*)d_in[5];
    const float* Whh  = (const float*)d_in[6];
    const float* b_ih = (const float*)d_in[7];
    const float* b_hh = (const float*)d_in[8];
    float* out = (float*)d_out;

    const int grid = (BB * 8) / 64;   // 512 one-wave blocks, 8 lanes/chain
    mlstm_kernel<<<grid, 64, 0, stream>>>(xb, h0, c0, Wmx, Wmh, Wih, Whh, b_ih, b_hh, out);
}